// Round 6
// baseline (187.027 us; speedup 1.0000x reference)
//
#include <hip/hip_runtime.h>
#include <hip/hip_bf16.h>

// Problem constants (match reference)
#define BATCH 32
#define NDIM  1024
#define NUSE  1022          // segments used in the mean (nseg - 1)
#define BLK   256
#define G     64            // row-groups per batch (2048 blocks = 8/CU)
#define ROWS  16            // rows per block = NDIM/G
#define RBLK  64            // reduce block = 1 wave
#define PSEG  1028          // 1024 partial slots + 4 zero-pad
#define PSTRIDE (2*PSEG)    // per-block partial stride in floats (8224 B, 16B-mult)

// Fully aligned 16-byte vector (triangle loads are 16B-aligned by construction).
typedef float f4  __attribute__((ext_vector_type(4), aligned(16)));
// 4-byte-aligned 16-byte vector (reduce's shifted partial reads).
typedef float f4a __attribute__((ext_vector_type(4), aligned(4)));

// ---------------------------------------------------------------------------
// Kernel 1: register-binned partial segment sums with ALIGNED quad loads.
// Rows i = g + 64m share o = (i+1)%4 (block-uniform). Thread t owns segments
// {4t-o .. 4t+3-o} and loads the 16B-aligned quad at column i+1-o+4t every
// row: one aligned global_load_dwordx4 per row per thread. Element r is
// valid iff 0 <= 4t+r-o <= 1022-i (one unsigned compare). Bins stored at
// slot 4t+r (segment = slot - o); reduce compensates with a per-g shift.
// ---------------------------------------------------------------------------
__global__ __launch_bounds__(BLK) void seg_partial_kernel(
        const float* __restrict__ S,     // (BATCH, NDIM, NDIM)
        float* __restrict__ part)        // (BATCH*G, PSTRIDE)
{
    const int b  = blockIdx.x >> 6;       // / G
    const int g  = blockIdx.x & (G - 1);  // % G
    const int t  = threadIdx.x;
    const int o  = (g + 1) & 3;           // (i+1) % 4 for every row of block
    const int d0 = (t << 2) - o;          // first owned segment (-3..-1 for t=0)

    float s0 = 0.f, s1 = 0.f, s2 = 0.f, s3 = 0.f;
    float q0 = 0.f, q1 = 0.f, q2 = 0.f, q3 = 0.f;

    // Row i = g + 64m; aligned quad base column = (i+1-o) + 4t.
    // Flat index = i*1024 + (i+1-o) + 4t; divisible by 4 -> 16B-aligned.
    const float* p = S + (size_t)b * NDIM * NDIM
                       + (size_t)g * NDIM + (g + 1 - o) + (t << 2);

    #pragma unroll
    for (int m = 0; m < ROWS; ++m) {
        const int i = g + (m << 6);
        if (i < NDIM - 1) {                     // uniform (false only g=63,m=15)
            const int urem = NDIM - 2 - i;      // last valid segment = 1022-i
            if (d0 <= urem) {                   // coherent lane cutoff
                // Max flat read = i*1024 + 1026 <= 1022*1024+1026 < 2^20: in
                // bounds within this batch (overreach masked below).
                f4 v = __builtin_nontemporal_load((const f4*)p);
                // valid iff 0 <= d0+r <= urem (unsigned trick covers both
                // below-diagonal (negative) and past-row-end).
                float v0 = ((unsigned)(d0 + 0) <= (unsigned)urem) ? v.x : 0.f;
                float v1 = ((unsigned)(d0 + 1) <= (unsigned)urem) ? v.y : 0.f;
                float v2 = ((unsigned)(d0 + 2) <= (unsigned)urem) ? v.z : 0.f;
                float v3 = ((unsigned)(d0 + 3) <= (unsigned)urem) ? v.w : 0.f;
                s0 += v0; q0 += v0 * v0;
                s1 += v1; q1 += v1 * v1;
                s2 += v2; q2 += v2 * v2;
                s3 += v3; q3 += v3 * v3;
            }
        }
        p += 64 * NDIM + 64;                    // next row of this block
    }

    float* pb = part + (size_t)blockIdx.x * PSTRIDE;
    ((f4*)pb)[t]          = (f4){s0, s1, s2, s3};   // sum slots [0,1024)
    ((f4*)(pb + PSEG))[t] = (f4){q0, q1, q2, q3};   // sq  slots [0,1024)
    if (t == 0) {                                    // zero the +4 pads
        f4 z = (f4){0.f, 0.f, 0.f, 0.f};
        *(f4*)(pb + 1024)        = z;
        *(f4*)(pb + PSEG + 1024) = z;
    }
}

// ---------------------------------------------------------------------------
// Kernel 2: 128 one-wave blocks = 32 batches x 4 segment-chunks. Thread t
// owns segments s0..s0+3 (s0 = c*256+4t). Group g stored segment s at slot
// s + o_g, so read the (possibly misaligned, L2-resident) quad at slot
// s0 + o_g; slot overreach lands in the zero pad. Fully unrolled, 128
// independent loads/thread. No LDS, no barrier.
// ---------------------------------------------------------------------------
__global__ __launch_bounds__(RBLK) void reduce_kernel(
        const float* __restrict__ part,  // (BATCH*G, PSTRIDE)
        float* __restrict__ cpart)       // (BATCH*4)
{
    const int b  = blockIdx.x >> 2;
    const int c  = blockIdx.x & 3;
    const int t  = threadIdx.x;              // 0..63
    const int s0 = (c << 8) + (t << 2);      // quad base segment, <= 1020

    f4 sum = {0.f, 0.f, 0.f, 0.f};
    f4 sq  = {0.f, 0.f, 0.f, 0.f};
    const float* p = part + (size_t)b * G * PSTRIDE;
    #pragma unroll
    for (int g = 0; g < G; ++g) {
        const int o = (g + 1) & 3;           // compile-time per unrolled g
        const float* pb = p + (size_t)g * PSTRIDE;
        // slot max = s0+o+3 <= 1026 < PSEG: pad absorbs the boundary.
        f4a a = *(const f4a*)(pb + s0 + o);
        f4a z = *(const f4a*)(pb + PSEG + s0 + o);
        sum += a;
        sq  += z;
    }

    float acc = 0.f;
    #pragma unroll
    for (int r = 0; r < 4; ++r) {
        const int s = s0 + r;
        if (s < NUSE) {
            float cnt  = (float)(NDIM - 1 - s);
            float mean = sum[r] / cnt;
            float var  = (sq[r] - cnt * mean * mean) / (cnt - 1.0f);
            acc += sqrtf(fmaxf(var, 0.0f)) * cnt * 0.05f;   // * cnt / 20
        }
    }

    #pragma unroll
    for (int off = 32; off > 0; off >>= 1)
        acc += __shfl_down(acc, off, 64);
    if (t == 0) cpart[blockIdx.x] = acc;
}

// ---------------------------------------------------------------------------
// Kernel 3: fold the 128 chunk partials -> scalar grand mean.
// ---------------------------------------------------------------------------
__global__ void final_kernel(const float* __restrict__ cpart,
                             float* __restrict__ out)
{
    float v = cpart[threadIdx.x] + cpart[threadIdx.x + 64];
    #pragma unroll
    for (int off = 32; off > 0; off >>= 1)
        v += __shfl_down(v, off, 64);
    if (threadIdx.x == 0)
        out[0] = v / (float)(BATCH * NUSE);
}

// ---------------------------------------------------------------------------
extern "C" void kernel_launch(void* const* d_in, const int* in_sizes, int n_in,
                              void* d_out, int out_size, void* d_ws, size_t ws_size,
                              hipStream_t stream) {
    const float* S = (const float*)d_in[0];
    float* out = (float*)d_out;

    float* part  = (float*)d_ws;                      // BATCH*G*PSTRIDE floats (16.8 MB)
    float* cpart = part + (size_t)BATCH * G * PSTRIDE; // 128 floats

    seg_partial_kernel<<<BATCH * G, BLK, 0, stream>>>(S, part);
    reduce_kernel<<<BATCH * 4, RBLK, 0, stream>>>(part, cpart);
    final_kernel<<<1, 64, 0, stream>>>(cpart, out);
}

// Round 7
// 185.945 us; speedup vs baseline: 1.0058x; 1.0058x over previous
//
#include <hip/hip_runtime.h>
#include <hip/hip_bf16.h>

// Problem constants (match reference)
#define BATCH 32
#define NDIM  1024
#define NSEGP 1024          // padded segment slots per partial (1023 real)
#define NUSE  1022          // segments used in the mean (nseg - 1)
#define BLK   256
#define G     64            // row-groups per batch (2048 blocks = 8/CU, 100% occ)
#define ROWS  16            // rows per block = NDIM/G
#define RBLK  64            // reduce block = 1 wave
#define RGRID (BATCH * 4)   // 128 reduce blocks

// 16-byte vector with only 4-byte alignment guarantee (row base shifts by i+1;
// R5 measured: HW handles dword-aligned dwordx4 at no cost — keep it simple).
typedef float f4a __attribute__((ext_vector_type(4), aligned(4)));
// Fully aligned 16-byte vector for the workspace.
typedef float f4  __attribute__((ext_vector_type(4), aligned(16)));

// ---------------------------------------------------------------------------
// Kernel 1: register-binned partial segment sums, quad ownership (R4 struct).
// Thread t owns segments {4t..4t+3}; for row i it reads columns
// i+1+4t .. i+1+4t+3 as ONE 16-byte nontemporal load (s = j-i-1 is
// i-invariant). 16 independent loads/thread, 8 blocks/CU for latency cover.
// Block 0 also zeroes the reduce-done counter (ws is poisoned 0xAA each
// replay); stream order guarantees visibility before reduce_kernel runs.
// ---------------------------------------------------------------------------
__global__ __launch_bounds__(BLK) void seg_partial_kernel(
        const float* __restrict__ S,     // (BATCH, NDIM, NDIM)
        float* __restrict__ part,        // (BATCH*G, 2, NSEGP)
        int* __restrict__ done_counter)
{
    if (blockIdx.x == 0 && threadIdx.x == 0) *done_counter = 0;

    const int b  = blockIdx.x >> 6;       // / G
    const int g  = blockIdx.x & (G - 1);  // % G
    const int c0 = threadIdx.x << 2;      // first owned segment

    float s0 = 0.f, s1 = 0.f, s2 = 0.f, s3 = 0.f;
    float q0 = 0.f, q1 = 0.f, q2 = 0.f, q3 = 0.f;

    // Row i = g + 64m; element (i, i+1+c0) at flat offset i*1024 + i+1 + c0.
    const float* p = S + (size_t)b * NDIM * NDIM + (size_t)g * (NDIM + 1) + 1 + c0;

    #pragma unroll
    for (int m = 0; m < ROWS; ++m) {
        const int i = g + (m << 6);
        if (i < NDIM - 1) {                  // uniform (false only g=63,m=15)
            const int rem = NDIM - 1 - i;    // valid elements in this row
            if (c0 < rem) {                  // coherent lane cutoff
                // Tail quad stays in-bounds: max flat index within batch is
                // 1022*1024 + 1023 + 1020 + 3 = 1048574 < 2^20.
                f4a v = __builtin_nontemporal_load((const f4a*)p);
                float v0 = v.x;                            // c0 < rem holds
                float v1 = (c0 + 1 < rem) ? v.y : 0.f;     // tail masks
                float v2 = (c0 + 2 < rem) ? v.z : 0.f;
                float v3 = (c0 + 3 < rem) ? v.w : 0.f;
                s0 += v0; q0 += v0 * v0;
                s1 += v1; q1 += v1 * v1;
                s2 += v2; q2 += v2 * v2;
                s3 += v3; q3 += v3 * v3;
            }
        }
        p += 64 * NDIM + 64;                 // next row handled by this block
    }

    float* psum = part + (size_t)blockIdx.x * (2 * NSEGP);
    ((f4*)psum)[threadIdx.x]           = (f4){s0, s1, s2, s3};
    ((f4*)(psum + NSEGP))[threadIdx.x] = (f4){q0, q1, q2, q3};
}

// ---------------------------------------------------------------------------
// Kernel 2: 128 one-wave blocks = 32 batches x 4 segment-chunks. Thread t
// owns segment quad s = c*256 + 4t .. +3; fully unrolled 64-way g reduction
// (128 independent float4 loads), finalize, wave-reduce -> chunk partial.
// Last block to finish (device-scope counter) folds the 128 chunk partials
// and writes the scalar — removes the 3rd kernel launch.
// ---------------------------------------------------------------------------
__global__ __launch_bounds__(RBLK) void reduce_kernel(
        const float* __restrict__ part,  // (BATCH*G, 2, NSEGP)
        float* __restrict__ cpart,       // (RGRID)
        int* __restrict__ done_counter,
        float* __restrict__ out)
{
    const int b  = blockIdx.x >> 2;
    const int c  = blockIdx.x & 3;
    const int t  = threadIdx.x;              // 0..63
    const int s0 = (c << 8) + (t << 2);      // quad base segment
    const int qi = s0 >> 2;                  // quad index within 1024 slots

    f4 sum = {0.f, 0.f, 0.f, 0.f};
    f4 sq  = {0.f, 0.f, 0.f, 0.f};
    const float* p = part + (size_t)b * G * (2 * NSEGP);
    #pragma unroll
    for (int g = 0; g < G; ++g) {
        f4 a = ((const f4*)(p + (size_t)g * (2 * NSEGP)))[qi];
        f4 z = ((const f4*)(p + (size_t)g * (2 * NSEGP) + NSEGP))[qi];
        sum += a;
        sq  += z;
    }

    float acc = 0.f;
    #pragma unroll
    for (int r = 0; r < 4; ++r) {
        const int s = s0 + r;
        if (s < NUSE) {
            float cnt  = (float)(NDIM - 1 - s);
            float mean = sum[r] / cnt;
            float var  = (sq[r] - cnt * mean * mean) / (cnt - 1.0f);
            acc += sqrtf(fmaxf(var, 0.0f)) * cnt * 0.05f;   // * cnt / 20
        }
    }

    #pragma unroll
    for (int off = 32; off > 0; off >>= 1)
        acc += __shfl_down(acc, off, 64);

    __shared__ bool last;
    if (t == 0) {
        cpart[blockIdx.x] = acc;
        __threadfence();                     // publish cpart (device scope)
        int prev = atomicAdd(done_counter, 1);
        last = (prev == RGRID - 1);
    }
    __syncthreads();

    if (last) {
        // Fold the 128 chunk partials -> scalar grand mean.
        float v = cpart[t] + cpart[t + 64];
        #pragma unroll
        for (int off = 32; off > 0; off >>= 1)
            v += __shfl_down(v, off, 64);
        if (t == 0)
            out[0] = v / (float)(BATCH * NUSE);
    }
}

// ---------------------------------------------------------------------------
extern "C" void kernel_launch(void* const* d_in, const int* in_sizes, int n_in,
                              void* d_out, int out_size, void* d_ws, size_t ws_size,
                              hipStream_t stream) {
    const float* S = (const float*)d_in[0];
    float* out = (float*)d_out;

    float* part  = (float*)d_ws;                         // BATCH*G*2*NSEGP floats (16.8 MB)
    float* cpart = part + (size_t)BATCH * G * 2 * NSEGP; // RGRID floats
    int*   done  = (int*)(cpart + RGRID);                // 1 int

    seg_partial_kernel<<<BATCH * G, BLK, 0, stream>>>(S, part, done);
    reduce_kernel<<<RGRID, RBLK, 0, stream>>>(part, cpart, done, out);
}